// Round 9
// baseline (93.598 us; speedup 1.0000x reference)
//
#include <hip/hip_runtime.h>

typedef float f4 __attribute__((ext_vector_type(4)));

// Uniform row pointer into concatenated v_t_d / v_l_d:
// [vmain(384) | v1(64) | v2(32) | v0(64)] along tokens
__device__ __forceinline__ const float* vd_row(const float* vmain, const float* v0,
                                               const float* v1, const float* v2,
                                               int b, int t) {
    if (t < 384)      return vmain + ((size_t)b * 384 + t) * 128;
    else if (t < 448) return v1    + ((size_t)b * 64 + (t - 384)) * 128;
    else if (t < 480) return v2    + ((size_t)b * 32 + (t - 448)) * 128;
    else              return v0    + ((size_t)b * 64 + (t - 480)) * 128;
}

// K_A: fused att+pair. Block = (d, b, so); 512 blocks x 256 thr = 2 blocks/CU.
// Phase A: both att rows at this (b,d) -> LDS rows[1088]. W row indexed with
//          block-uniform d -> compiler scalarizes to s_load (SGPR operands, no
//          VGPR pressure). Row loads are per-lane f4 gathers (L2-resident).
// Phase C: own `so` only, lrelu factorization, otherr via b128 LDS broadcast.
// d==0,so==0 blocks also zero the x4 slabs (kernel-boundary ordered vs k_atte).
__global__ __launch_bounds__(256, 2) void k_attpair(
    const float* __restrict__ v0, const float* __restrict__ v1, const float* __restrict__ v2,
    const float* __restrict__ vt, const float* __restrict__ vl,
    const float* __restrict__ Wt, const float* __restrict__ bt,
    const float* __restrict__ Wl, const float* __restrict__ bl,
    float* __restrict__ S, float* __restrict__ x4)
{
    const int d = blockIdx.x, b = blockIdx.y, so = blockIdx.z;
    const int tid = threadIdx.x, lane = tid & 63, wvid = tid >> 6;
    __shared__ float rows[1088];            // [0..543]=trow, [544..1087]=lrow
    __shared__ float red[4];

    if (d == 0 && so == 0) {
        for (int i = tid; i < 1024; i += 256)
            x4[(i >> 8) * 512 + b * 256 + (i & 255)] = 0.f;
    }

    // ---- Phase A: att rows for both sides ----
    #pragma unroll 1
    for (int side = 0; side < 2; ++side) {
        const float* W     = side ? Wl : Wt;
        const float* vmain = side ? vl : vt;
        const float* Wrow  = W + d * 128;            // block-uniform -> s_load
        const float  bv    = (side ? bl : bt)[d];
        for (int t = tid; t < 544; t += 256) {
            const f4* row = (const f4*)vd_row(vmain, v0, v1, v2, b, t);
            float a0 = 0.f, a1 = 0.f, a2 = 0.f, a3 = 0.f;
            #pragma unroll
            for (int kc = 0; kc < 32; kc += 4) {
                f4 r0 = row[kc], r1 = row[kc+1], r2 = row[kc+2], r3 = row[kc+3];
                a0 += r0[0]*Wrow[kc*4+ 0] + r0[1]*Wrow[kc*4+ 1] + r0[2]*Wrow[kc*4+ 2] + r0[3]*Wrow[kc*4+ 3];
                a1 += r1[0]*Wrow[kc*4+ 4] + r1[1]*Wrow[kc*4+ 5] + r1[2]*Wrow[kc*4+ 6] + r1[3]*Wrow[kc*4+ 7];
                a2 += r2[0]*Wrow[kc*4+ 8] + r2[1]*Wrow[kc*4+ 9] + r2[2]*Wrow[kc*4+10] + r2[3]*Wrow[kc*4+11];
                a3 += r3[0]*Wrow[kc*4+12] + r3[1]*Wrow[kc*4+13] + r3[2]*Wrow[kc*4+14] + r3[3]*Wrow[kc*4+15];
            }
            rows[side * 544 + t] = bv + ((a0 + a1) + (a2 + a3));
        }
    }
    __syncthreads();

    // ---- Phase B: sum of the other-side row ----
    const float* selfr  = rows + so * 544;
    const float* otherr = rows + (1 - so) * 544;
    float p = 0.f;
    for (int i = tid; i < 544; i += 256) p += otherr[i];
    #pragma unroll
    for (int off = 32; off > 0; off >>= 1) p += __shfl_down(p, off, 64);
    if (lane == 0) red[wvid] = p;
    __syncthreads();
    const float sum_o = red[0] + red[1] + red[2] + red[3];

    // ---- Phase C: pairwise |.| mean for own so; otherr b128 broadcast reads ----
    const f4* or4 = (const f4*)otherr;
    for (int t = tid; t < 544; t += 256) {
        float c = selfr[t];
        float s0 = 0.f, s1 = 0.f, s2 = 0.f, s3 = 0.f;
        #pragma unroll 4
        for (int l4 = 0; l4 < 136; ++l4) {
            f4 o = or4[l4];
            s0 += fabsf(c + o[0]);
            s1 += fabsf(c + o[1]);
            s2 += fabsf(c + o[2]);
            s3 += fabsf(c + o[3]);
        }
        float s = (s0 + s1) + (s2 + s3);
        S[((size_t)(so * 2 + b) * 544 + t) * 128 + d] =
            (0.505f * (544.f * c + sum_o) + 0.495f * s) * (1.0f / 544.f);
    }
}

// K_B: atte = sigmoid(S @ Wa^T + ba) -> outputs 1/2; gated value atomicAdd into
// slab x4[t&3] (chain depth 136). srow is block-uniform -> scalar loads.
__global__ __launch_bounds__(128) void k_atte(const float* __restrict__ S, const float* __restrict__ Wa,
                                              const float* __restrict__ ba,
                                              const float* __restrict__ v0, const float* __restrict__ v1,
                                              const float* __restrict__ v2, const float* __restrict__ vt,
                                              const float* __restrict__ vl,
                                              float* __restrict__ out, float* __restrict__ x4) {
    int t = blockIdx.x, b = blockIdx.y, side = blockIdx.z;
    int d = threadIdx.x;
    const float* srow = S + ((size_t)(side * 2 + b) * 544 + t) * 128;
    float acc = ba[d];
    const f4* wrow = (const f4*)(Wa + d * 128);
    #pragma unroll
    for (int kc = 0; kc < 32; ++kc) {
        f4 wv = wrow[kc];
        f4 sv = *(const f4*)(srow + kc * 4);
        acc += sv[0] * wv[0] + sv[1] * wv[1] + sv[2] * wv[2] + sv[3] * wv[3];
    }
    float atte = 1.f / (1.f + expf(-acc));
    out[4 + side * 139264 + ((size_t)b * 544 + t) * 128 + d] = atte;
    const float* vrow = vd_row(side ? vl : vt, v0, v1, v2, b, t);
    atomicAdd(&x4[(t & 3) * 512 + b * 256 + side * 128 + d], vrow[d] * (0.5f + atte));
}

// K_C: fc1 — one wave per output, x assembled from the 4 slabs on load.
__global__ __launch_bounds__(256) void k_fc1(const float* __restrict__ x4, const float* __restrict__ W1,
                                             const float* __restrict__ b1, float* __restrict__ f1v) {
    int wave = blockIdx.x * 4 + (threadIdx.x >> 6);   // 0..2047
    int lane = threadIdx.x & 63;
    int b = wave >> 10, o = wave & 1023;
    f4 iv = ((const f4*)(x4 + 0 * 512 + b * 256))[lane]
          + ((const f4*)(x4 + 1 * 512 + b * 256))[lane]
          + ((const f4*)(x4 + 2 * 512 + b * 256))[lane]
          + ((const f4*)(x4 + 3 * 512 + b * 256))[lane];
    f4 wv = ((const f4*)(W1 + (size_t)o * 256))[lane];
    float acc = wv[0]*iv[0] + wv[1]*iv[1] + wv[2]*iv[2] + wv[3]*iv[3];
    #pragma unroll
    for (int off = 32; off > 0; off >>= 1) acc += __shfl_down(acc, off, 64);
    if (lane == 0) {
        acc += b1[o];
        f1v[wave] = acc > 0.f ? acc : 0.01f * acc;
    }
}

// K_D: fc2 — one wave per output, K=1024 (4 f4/lane), butterfly reduce.
__global__ __launch_bounds__(256) void k_fc2(const float* __restrict__ f1v, const float* __restrict__ W2,
                                             const float* __restrict__ b2, float* __restrict__ f2v) {
    int wave = blockIdx.x * 4 + (threadIdx.x >> 6);   // 0..1023
    int lane = threadIdx.x & 63;
    int b = wave >> 9, o = wave & 511;
    const f4* w2r = (const f4*)(W2 + (size_t)o * 1024);
    const f4* i2r = (const f4*)(f1v + b * 1024);
    float acc = 0.f;
    #pragma unroll
    for (int c2 = 0; c2 < 4; ++c2) {
        f4 wv = w2r[c2 * 64 + lane];
        f4 iv = i2r[c2 * 64 + lane];
        acc += wv[0]*iv[0] + wv[1]*iv[1] + wv[2]*iv[2] + wv[3]*iv[3];
    }
    #pragma unroll
    for (int off = 32; off > 0; off >>= 1) acc += __shfl_down(acc, off, 64);
    if (lane == 0) {
        acc += b2[o];
        f2v[wave] = acc > 0.f ? acc : 0.01f * acc;
    }
}

// K_E: fc3 (both batches) + predict, one block (256 threads), LDS handoff.
__global__ __launch_bounds__(256) void k_f3p(const float* __restrict__ f2v, const float* __restrict__ W3,
                                             const float* __restrict__ b3, const float* __restrict__ Wo,
                                             const float* __restrict__ bo, float* __restrict__ out) {
    __shared__ float f3s[512];
    int tid = threadIdx.x;
    const f4* w3r = (const f4*)(W3 + (size_t)tid * 512);
    const f4* f20 = (const f4*)(f2v);
    const f4* f21 = (const f4*)(f2v + 512);
    float a0 = b3[tid], a1 = a0;
    #pragma unroll 4
    for (int c2 = 0; c2 < 128; ++c2) {
        f4 wv4 = w3r[c2];
        f4 i0 = f20[c2];
        f4 i1 = f21[c2];
        a0 += wv4[0]*i0[0] + wv4[1]*i0[1] + wv4[2]*i0[2] + wv4[3]*i0[3];
        a1 += wv4[0]*i1[0] + wv4[1]*i1[1] + wv4[2]*i1[2] + wv4[3]*i1[3];
    }
    f3s[tid]       = a0 > 0.f ? a0 : 0.01f * a0;
    f3s[256 + tid] = a1 > 0.f ? a1 : 0.01f * a1;
    __syncthreads();
    int wvid = tid >> 6, lane = tid & 63;
    int b = wvid >> 1, o = wvid & 1;                  // 4 waves -> 4 outputs
    f4 wo4 = ((const f4*)(Wo + o * 256))[lane];
    float acc = wo4[0]*f3s[b*256 + lane*4]     + wo4[1]*f3s[b*256 + lane*4 + 1]
              + wo4[2]*f3s[b*256 + lane*4 + 2] + wo4[3]*f3s[b*256 + lane*4 + 3];
    #pragma unroll
    for (int off = 32; off > 0; off >>= 1) acc += __shfl_down(acc, off, 64);
    if (lane == 0) out[b * 2 + o] = acc + bo[o];
}

extern "C" void kernel_launch(void* const* d_in, const int* in_sizes, int n_in,
                              void* d_out, int out_size, void* d_ws, size_t ws_size,
                              hipStream_t stream) {
    (void)in_sizes; (void)n_in; (void)out_size; (void)ws_size;
    const float* v0 = (const float*)d_in[0];
    const float* v1 = (const float*)d_in[1];
    const float* v2 = (const float*)d_in[2];
    const float* vt = (const float*)d_in[3];
    const float* vl = (const float*)d_in[4];
    const float* Wt = (const float*)d_in[5];
    const float* bt = (const float*)d_in[6];
    const float* Wl = (const float*)d_in[7];
    const float* bl = (const float*)d_in[8];
    const float* Wa = (const float*)d_in[9];
    const float* ba = (const float*)d_in[10];
    const float* W1 = (const float*)d_in[11];
    const float* b1 = (const float*)d_in[12];
    const float* W2 = (const float*)d_in[13];
    const float* b2 = (const float*)d_in[14];
    const float* W3 = (const float*)d_in[15];
    const float* b3 = (const float*)d_in[16];
    const float* Wo = (const float*)d_in[17];
    const float* bo = (const float*)d_in[18];

    float* ws   = (float*)d_ws;
    float* S    = ws;                 // [2][2][544][128] = 278528
    float* x4   = ws + 278528;        // [4][2][256]      = 2048
    float* f1v  = ws + 280576;        // [2][1024]
    float* f2v  = ws + 282624;        // [2][512]
    float* out = (float*)d_out;

    k_attpair<<<dim3(128, 2, 2), 256, 0, stream>>>(v0, v1, v2, vt, vl, Wt, bt, Wl, bl, S, x4);
    k_atte<<<dim3(544, 2, 2), 128, 0, stream>>>(S, Wa, ba, v0, v1, v2, vt, vl, out, x4);
    k_fc1<<<512, 256, 0, stream>>>(x4, W1, b1, f1v);
    k_fc2<<<256, 256, 0, stream>>>(f1v, W2, b2, f2v);
    k_f3p<<<1, 256, 0, stream>>>(f2v, W3, b3, Wo, bo, out);
}

// Round 10
// 87.708 us; speedup vs baseline: 1.0672x; 1.0672x over previous
//
#include <hip/hip_runtime.h>

typedef float f4 __attribute__((ext_vector_type(4)));

// Uniform row pointer into concatenated v_t_d / v_l_d:
// [vmain(384) | v1(64) | v2(32) | v0(64)] along tokens
__device__ __forceinline__ const float* vd_row(const float* vmain, const float* v0,
                                               const float* v1, const float* v2,
                                               int b, int t) {
    if (t < 384)      return vmain + ((size_t)b * 384 + t) * 128;
    else if (t < 448) return v1    + ((size_t)b * 64 + (t - 384)) * 128;
    else if (t < 480) return v2    + ((size_t)b * 32 + (t - 448)) * 128;
    else              return v0    + ((size_t)b * 64 + (t - 480)) * 128;
}

// K1: attT[side][b][d][t] = bias[d] + sum_k row[k] * W[d][k]  (t-contiguous store
// so k_pair can stage coalesced). row[] wave-uniform -> s_load broadcast; W row
// per-lane gather from L1 (64 KB, resident). t==0/side==0 blocks zero x4 slabs.
__global__ __launch_bounds__(128) void k_att(const float* __restrict__ v0, const float* __restrict__ v1,
                                             const float* __restrict__ v2, const float* __restrict__ vt,
                                             const float* __restrict__ vl,
                                             const float* __restrict__ Wt, const float* __restrict__ bt,
                                             const float* __restrict__ Wl, const float* __restrict__ bl,
                                             float* __restrict__ attT, float* __restrict__ x4) {
    int t = blockIdx.x, b = blockIdx.y, side = blockIdx.z;
    int d = threadIdx.x;
    if (t == 0 && side == 0) {
        for (int i = d; i < 1024; i += 128)
            x4[(i >> 8) * 512 + b * 256 + (i & 255)] = 0.f;
    }
    const float* row  = vd_row(side ? vl : vt, v0, v1, v2, b, t);
    const float* W    = side ? Wl : Wt;
    const float* bias = side ? bl : bt;
    float acc = bias[d];
    const f4* wrow = (const f4*)(W + d * 128);
    #pragma unroll
    for (int kc = 0; kc < 32; ++kc) {
        f4 wv = wrow[kc];
        #pragma unroll
        for (int j = 0; j < 4; ++j) acc += row[kc * 4 + j] * wv[j];
    }
    attT[((size_t)(side * 2 + b) * 128 + d) * 544 + t] = acc;
}

// K2: S[so][b][t][d]; so=0: mean over l of lrelu(tA+lA); so=1: mean over t.
// lrelu(x)=0.505x+0.495|x| => sum_l lrelu(c+o[l]) = 0.505*(544c+sum_o)+0.495*sum|c+o[l]|
// Rows staged to LDS with COALESCED contiguous loads; inner loop reads LDS
// broadcast f4 (conflict-free) -> 2-VALU/element floor.
__global__ __launch_bounds__(256, 2) void k_pair(const float* __restrict__ attT,
                                                 float* __restrict__ S) {
    const int d = blockIdx.x, b = blockIdx.y, so = blockIdx.z;
    const int tid = threadIdx.x, lane = tid & 63, wvid = tid >> 6;
    __shared__ float rows[1088];            // [0..543]=trow, [544..1087]=lrow
    __shared__ float red[4];
    const float* trow_g = attT + ((size_t)(0 * 2 + b) * 128 + d) * 544;
    const float* lrow_g = attT + ((size_t)(1 * 2 + b) * 128 + d) * 544;
    for (int i = tid; i < 544; i += 256) {
        rows[i]       = trow_g[i];
        rows[544 + i] = lrow_g[i];
    }
    __syncthreads();

    const float* selfr  = rows + so * 544;
    const float* otherr = rows + (1 - so) * 544;
    float p = 0.f;
    for (int i = tid; i < 544; i += 256) p += otherr[i];
    #pragma unroll
    for (int off = 32; off > 0; off >>= 1) p += __shfl_down(p, off, 64);
    if (lane == 0) red[wvid] = p;
    __syncthreads();
    const float sum_o = red[0] + red[1] + red[2] + red[3];

    const f4* or4 = (const f4*)otherr;
    for (int t = tid; t < 544; t += 256) {
        float c = selfr[t];
        float s0 = 0.f, s1 = 0.f, s2 = 0.f, s3 = 0.f;
        #pragma unroll 4
        for (int l4 = 0; l4 < 136; ++l4) {
            f4 o = or4[l4];
            s0 += fabsf(c + o[0]);
            s1 += fabsf(c + o[1]);
            s2 += fabsf(c + o[2]);
            s3 += fabsf(c + o[3]);
        }
        float s = (s0 + s1) + (s2 + s3);
        S[((size_t)(so * 2 + b) * 544 + t) * 128 + d] =
            (0.505f * (544.f * c + sum_o) + 0.495f * s) * (1.0f / 544.f);
    }
}

// K3: atte = sigmoid(S @ Wa^T + ba) -> outputs 1/2; gated value atomicAdd into
// slab x4[t&3] (chain depth 136). srow is block-uniform -> scalar loads.
__global__ __launch_bounds__(128) void k_atte(const float* __restrict__ S, const float* __restrict__ Wa,
                                              const float* __restrict__ ba,
                                              const float* __restrict__ v0, const float* __restrict__ v1,
                                              const float* __restrict__ v2, const float* __restrict__ vt,
                                              const float* __restrict__ vl,
                                              float* __restrict__ out, float* __restrict__ x4) {
    int t = blockIdx.x, b = blockIdx.y, side = blockIdx.z;
    int d = threadIdx.x;
    const float* srow = S + ((size_t)(side * 2 + b) * 544 + t) * 128;
    float acc = ba[d];
    const f4* wrow = (const f4*)(Wa + d * 128);
    #pragma unroll
    for (int kc = 0; kc < 32; ++kc) {
        f4 wv = wrow[kc];
        f4 sv = *(const f4*)(srow + kc * 4);
        acc += sv[0] * wv[0] + sv[1] * wv[1] + sv[2] * wv[2] + sv[3] * wv[3];
    }
    float atte = 1.f / (1.f + expf(-acc));
    out[4 + side * 139264 + ((size_t)b * 544 + t) * 128 + d] = atte;
    const float* vrow = vd_row(side ? vl : vt, v0, v1, v2, b, t);
    atomicAdd(&x4[(t & 3) * 512 + b * 256 + side * 128 + d], vrow[d] * (0.5f + atte));
}

// K4: fc1 — one wave per output, x assembled from the 4 slabs on load.
__global__ __launch_bounds__(256) void k_fc1(const float* __restrict__ x4, const float* __restrict__ W1,
                                             const float* __restrict__ b1, float* __restrict__ f1v) {
    int wave = blockIdx.x * 4 + (threadIdx.x >> 6);   // 0..2047
    int lane = threadIdx.x & 63;
    int b = wave >> 10, o = wave & 1023;
    f4 iv = ((const f4*)(x4 + 0 * 512 + b * 256))[lane]
          + ((const f4*)(x4 + 1 * 512 + b * 256))[lane]
          + ((const f4*)(x4 + 2 * 512 + b * 256))[lane]
          + ((const f4*)(x4 + 3 * 512 + b * 256))[lane];
    f4 wv = ((const f4*)(W1 + (size_t)o * 256))[lane];
    float acc = wv[0]*iv[0] + wv[1]*iv[1] + wv[2]*iv[2] + wv[3]*iv[3];
    #pragma unroll
    for (int off = 32; off > 0; off >>= 1) acc += __shfl_down(acc, off, 64);
    if (lane == 0) {
        acc += b1[o];
        f1v[wave] = acc > 0.f ? acc : 0.01f * acc;
    }
}

// K5: fc2 — one wave per output, K=1024 (4 f4/lane), butterfly reduce.
__global__ __launch_bounds__(256) void k_fc2(const float* __restrict__ f1v, const float* __restrict__ W2,
                                             const float* __restrict__ b2, float* __restrict__ f2v) {
    int wave = blockIdx.x * 4 + (threadIdx.x >> 6);   // 0..1023
    int lane = threadIdx.x & 63;
    int b = wave >> 9, o = wave & 511;
    const f4* w2r = (const f4*)(W2 + (size_t)o * 1024);
    const f4* i2r = (const f4*)(f1v + b * 1024);
    float acc = 0.f;
    #pragma unroll
    for (int c2 = 0; c2 < 4; ++c2) {
        f4 wv = w2r[c2 * 64 + lane];
        f4 iv = i2r[c2 * 64 + lane];
        acc += wv[0]*iv[0] + wv[1]*iv[1] + wv[2]*iv[2] + wv[3]*iv[3];
    }
    #pragma unroll
    for (int off = 32; off > 0; off >>= 1) acc += __shfl_down(acc, off, 64);
    if (lane == 0) {
        acc += b2[o];
        f2v[wave] = acc > 0.f ? acc : 0.01f * acc;
    }
}

// K6: fc3 (both batches) + predict, one block (256 threads), LDS handoff.
__global__ __launch_bounds__(256) void k_f3p(const float* __restrict__ f2v, const float* __restrict__ W3,
                                             const float* __restrict__ b3, const float* __restrict__ Wo,
                                             const float* __restrict__ bo, float* __restrict__ out) {
    __shared__ float f3s[512];
    int tid = threadIdx.x;
    const f4* w3r = (const f4*)(W3 + (size_t)tid * 512);
    const f4* f20 = (const f4*)(f2v);
    const f4* f21 = (const f4*)(f2v + 512);
    float a0 = b3[tid], a1 = a0;
    #pragma unroll 4
    for (int c2 = 0; c2 < 128; ++c2) {
        f4 wv4 = w3r[c2];
        f4 i0 = f20[c2];
        f4 i1 = f21[c2];
        a0 += wv4[0]*i0[0] + wv4[1]*i0[1] + wv4[2]*i0[2] + wv4[3]*i0[3];
        a1 += wv4[0]*i1[0] + wv4[1]*i1[1] + wv4[2]*i1[2] + wv4[3]*i1[3];
    }
    f3s[tid]       = a0 > 0.f ? a0 : 0.01f * a0;
    f3s[256 + tid] = a1 > 0.f ? a1 : 0.01f * a1;
    __syncthreads();
    int wvid = tid >> 6, lane = tid & 63;
    int b = wvid >> 1, o = wvid & 1;                  // 4 waves -> 4 outputs
    f4 wo4 = ((const f4*)(Wo + o * 256))[lane];
    float acc = wo4[0]*f3s[b*256 + lane*4]     + wo4[1]*f3s[b*256 + lane*4 + 1]
              + wo4[2]*f3s[b*256 + lane*4 + 2] + wo4[3]*f3s[b*256 + lane*4 + 3];
    #pragma unroll
    for (int off = 32; off > 0; off >>= 1) acc += __shfl_down(acc, off, 64);
    if (lane == 0) out[b * 2 + o] = acc + bo[o];
}

extern "C" void kernel_launch(void* const* d_in, const int* in_sizes, int n_in,
                              void* d_out, int out_size, void* d_ws, size_t ws_size,
                              hipStream_t stream) {
    (void)in_sizes; (void)n_in; (void)out_size; (void)ws_size;
    const float* v0 = (const float*)d_in[0];
    const float* v1 = (const float*)d_in[1];
    const float* v2 = (const float*)d_in[2];
    const float* vt = (const float*)d_in[3];
    const float* vl = (const float*)d_in[4];
    const float* Wt = (const float*)d_in[5];
    const float* bt = (const float*)d_in[6];
    const float* Wl = (const float*)d_in[7];
    const float* bl = (const float*)d_in[8];
    const float* Wa = (const float*)d_in[9];
    const float* ba = (const float*)d_in[10];
    const float* W1 = (const float*)d_in[11];
    const float* b1 = (const float*)d_in[12];
    const float* W2 = (const float*)d_in[13];
    const float* b2 = (const float*)d_in[14];
    const float* W3 = (const float*)d_in[15];
    const float* b3 = (const float*)d_in[16];
    const float* Wo = (const float*)d_in[17];
    const float* bo = (const float*)d_in[18];

    float* ws   = (float*)d_ws;
    float* attT = ws;                 // [2][2][128][544] = 278528
    float* S    = ws + 278528;        // [2][2][544][128] = 278528
    float* x4   = ws + 557056;        // [4][2][256]      = 2048
    float* f1v  = ws + 559104;        // [2][1024]
    float* f2v  = ws + 561152;        // [2][512]
    float* out = (float*)d_out;

    k_att<<<dim3(544, 2, 2), 128, 0, stream>>>(v0, v1, v2, vt, vl, Wt, bt, Wl, bl, attT, x4);
    k_pair<<<dim3(128, 2, 2), 256, 0, stream>>>(attT, S);
    k_atte<<<dim3(544, 2, 2), 128, 0, stream>>>(S, Wa, ba, v0, v1, v2, vt, vl, out, x4);
    k_fc1<<<512, 256, 0, stream>>>(x4, W1, b1, f1v);
    k_fc2<<<256, 256, 0, stream>>>(f1v, W2, b2, f2v);
    k_f3p<<<1, 256, 0, stream>>>(f2v, W3, b3, Wo, bo, out);
}

// Round 11
// 62.043 us; speedup vs baseline: 1.5086x; 1.4137x over previous
//
#include <hip/hip_runtime.h>

typedef float f4 __attribute__((ext_vector_type(4)));

// Uniform row pointer into concatenated v_t_d / v_l_d:
// [vmain(384) | v1(64) | v2(32) | v0(64)] along tokens
__device__ __forceinline__ const float* vd_row(const float* vmain, const float* v0,
                                               const float* v1, const float* v2,
                                               int b, int t) {
    if (t < 384)      return vmain + ((size_t)b * 384 + t) * 128;
    else if (t < 448) return v1    + ((size_t)b * 64 + (t - 384)) * 128;
    else if (t < 480) return v2    + ((size_t)b * 32 + (t - 448)) * 128;
    else              return v0    + ((size_t)b * 64 + (t - 480)) * 128;
}

// K0: WT[m][k][d] = W_m[d][k]. The ONLY divergent W reads left (384 instrs total);
// every consumer henceforth reads WT coalesced.
__global__ __launch_bounds__(128) void k_tr(const float* __restrict__ Wt, const float* __restrict__ Wl,
                                            const float* __restrict__ Wa, float* __restrict__ WT) {
    int k = blockIdx.x, m = blockIdx.y, d = threadIdx.x;
    const float* src = m == 0 ? Wt : (m == 1 ? Wl : Wa);
    WT[((size_t)m * 128 + k) * 128 + d] = src[d * 128 + k];
}

// K1: att, 4 tokens per block. Rows staged in LDS (coalesced), consumed as b128
// broadcasts; WT read coalesced (lane = d); one w-load feeds 4 FMAs.
// tc==0/side==0 blocks zero the x4 slabs.
__global__ __launch_bounds__(128) void k_att(const float* __restrict__ v0, const float* __restrict__ v1,
                                             const float* __restrict__ v2, const float* __restrict__ vt,
                                             const float* __restrict__ vl,
                                             const float* __restrict__ WT,
                                             const float* __restrict__ bt, const float* __restrict__ bl,
                                             float* __restrict__ attT, float* __restrict__ x4) {
    int tc = blockIdx.x, b = blockIdx.y, side = blockIdx.z;
    int d = threadIdx.x;
    __shared__ float rows[4][128];
    if (tc == 0 && side == 0) {
        for (int i = d; i < 1024; i += 128)
            x4[(i >> 8) * 512 + b * 256 + (i & 255)] = 0.f;
    }
    const float* vmain = side ? vl : vt;
    #pragma unroll
    for (int i = 0; i < 4; ++i)
        rows[i][d] = vd_row(vmain, v0, v1, v2, b, tc * 4 + i)[d];
    __syncthreads();
    const float* WTs = WT + (size_t)side * 16384;
    float bv = (side ? bl : bt)[d];
    float a0 = bv, a1 = bv, a2 = bv, a3 = bv;
    #pragma unroll 4
    for (int kc = 0; kc < 32; ++kc) {
        f4 r0 = *(const f4*)&rows[0][kc * 4];
        f4 r1 = *(const f4*)&rows[1][kc * 4];
        f4 r2 = *(const f4*)&rows[2][kc * 4];
        f4 r3 = *(const f4*)&rows[3][kc * 4];
        float w0 = WTs[(kc * 4 + 0) * 128 + d];
        float w1 = WTs[(kc * 4 + 1) * 128 + d];
        float w2 = WTs[(kc * 4 + 2) * 128 + d];
        float w3 = WTs[(kc * 4 + 3) * 128 + d];
        a0 += r0[0] * w0 + r0[1] * w1 + r0[2] * w2 + r0[3] * w3;
        a1 += r1[0] * w0 + r1[1] * w1 + r1[2] * w2 + r1[3] * w3;
        a2 += r2[0] * w0 + r2[1] * w1 + r2[2] * w2 + r2[3] * w3;
        a3 += r3[0] * w0 + r3[1] * w1 + r3[2] * w2 + r3[3] * w3;
    }
    size_t base = ((size_t)(side * 2 + b) * 128 + d) * 544 + tc * 4;
    attT[base + 0] = a0; attT[base + 1] = a1; attT[base + 2] = a2; attT[base + 3] = a3;
}

// K2: S[so][b][t][d]; lrelu(x)=0.505x+0.495|x| => sum_l lrelu(c+o[l]) =
// 0.505*(544c+sum_o)+0.495*sum|c+o[l]|. Rows staged coalesced; inner loop LDS
// broadcast f4 -> 2-VALU/element floor.
__global__ __launch_bounds__(256, 2) void k_pair(const float* __restrict__ attT,
                                                 float* __restrict__ S) {
    const int d = blockIdx.x, b = blockIdx.y, so = blockIdx.z;
    const int tid = threadIdx.x, lane = tid & 63, wvid = tid >> 6;
    __shared__ float rows[1088];            // [0..543]=trow, [544..1087]=lrow
    __shared__ float red[4];
    const float* trow_g = attT + ((size_t)(0 * 2 + b) * 128 + d) * 544;
    const float* lrow_g = attT + ((size_t)(1 * 2 + b) * 128 + d) * 544;
    for (int i = tid; i < 544; i += 256) {
        rows[i]       = trow_g[i];
        rows[544 + i] = lrow_g[i];
    }
    __syncthreads();

    const float* selfr  = rows + so * 544;
    const float* otherr = rows + (1 - so) * 544;
    float p = 0.f;
    for (int i = tid; i < 544; i += 256) p += otherr[i];
    #pragma unroll
    for (int off = 32; off > 0; off >>= 1) p += __shfl_down(p, off, 64);
    if (lane == 0) red[wvid] = p;
    __syncthreads();
    const float sum_o = red[0] + red[1] + red[2] + red[3];

    const f4* or4 = (const f4*)otherr;
    for (int t = tid; t < 544; t += 256) {
        float c = selfr[t];
        float s0 = 0.f, s1 = 0.f, s2 = 0.f, s3 = 0.f;
        #pragma unroll 4
        for (int l4 = 0; l4 < 136; ++l4) {
            f4 o = or4[l4];
            s0 += fabsf(c + o[0]);
            s1 += fabsf(c + o[1]);
            s2 += fabsf(c + o[2]);
            s3 += fabsf(c + o[3]);
        }
        float s = (s0 + s1) + (s2 + s3);
        S[((size_t)(so * 2 + b) * 544 + t) * 128 + d] =
            (0.505f * (544.f * c + sum_o) + 0.495f * s) * (1.0f / 544.f);
    }
}

// K3: atte = sigmoid(S @ Wa^T + ba), 4 tokens per block; WaT coalesced, S rows
// staged coalesced in LDS; gated sum over 4 tokens -> ONE atomic per thread into
// slab tc&3 (chain depth 34).
__global__ __launch_bounds__(128) void k_atte(const float* __restrict__ S, const float* __restrict__ WT,
                                              const float* __restrict__ ba,
                                              const float* __restrict__ v0, const float* __restrict__ v1,
                                              const float* __restrict__ v2, const float* __restrict__ vt,
                                              const float* __restrict__ vl,
                                              float* __restrict__ out, float* __restrict__ x4) {
    int tc = blockIdx.x, b = blockIdx.y, side = blockIdx.z;
    int d = threadIdx.x;
    __shared__ float srows[4][128];
    const float* sbase = S + ((size_t)(side * 2 + b) * 544 + tc * 4) * 128;
    #pragma unroll
    for (int i = 0; i < 4; ++i) srows[i][d] = sbase[i * 128 + d];
    __syncthreads();
    const float* WaT = WT + 2 * 16384;
    float bv = ba[d];
    float a0 = bv, a1 = bv, a2 = bv, a3 = bv;
    #pragma unroll 4
    for (int kc = 0; kc < 32; ++kc) {
        f4 r0 = *(const f4*)&srows[0][kc * 4];
        f4 r1 = *(const f4*)&srows[1][kc * 4];
        f4 r2 = *(const f4*)&srows[2][kc * 4];
        f4 r3 = *(const f4*)&srows[3][kc * 4];
        float w0 = WaT[(kc * 4 + 0) * 128 + d];
        float w1 = WaT[(kc * 4 + 1) * 128 + d];
        float w2 = WaT[(kc * 4 + 2) * 128 + d];
        float w3 = WaT[(kc * 4 + 3) * 128 + d];
        a0 += r0[0] * w0 + r0[1] * w1 + r0[2] * w2 + r0[3] * w3;
        a1 += r1[0] * w0 + r1[1] * w1 + r1[2] * w2 + r1[3] * w3;
        a2 += r2[0] * w0 + r2[1] * w1 + r2[2] * w2 + r2[3] * w3;
        a3 += r3[0] * w0 + r3[1] * w1 + r3[2] * w2 + r3[3] * w3;
    }
    const float* vmain = side ? vl : vt;
    float* ob = out + 4 + (size_t)side * 139264 + ((size_t)b * 544 + tc * 4) * 128 + d;
    float xpart = 0.f;
    float accs[4] = {a0, a1, a2, a3};
    #pragma unroll
    for (int i = 0; i < 4; ++i) {
        float atte = 1.f / (1.f + expf(-accs[i]));
        ob[i * 128] = atte;
        xpart += vd_row(vmain, v0, v1, v2, b, tc * 4 + i)[d] * (0.5f + atte);
    }
    atomicAdd(&x4[(tc & 3) * 512 + b * 256 + side * 128 + d], xpart);
}

// K4: fc1 — one wave per output, x assembled from the 4 slabs on load.
__global__ __launch_bounds__(256) void k_fc1(const float* __restrict__ x4, const float* __restrict__ W1,
                                             const float* __restrict__ b1, float* __restrict__ f1v) {
    int wave = blockIdx.x * 4 + (threadIdx.x >> 6);   // 0..2047
    int lane = threadIdx.x & 63;
    int b = wave >> 10, o = wave & 1023;
    f4 iv = ((const f4*)(x4 + 0 * 512 + b * 256))[lane]
          + ((const f4*)(x4 + 1 * 512 + b * 256))[lane]
          + ((const f4*)(x4 + 2 * 512 + b * 256))[lane]
          + ((const f4*)(x4 + 3 * 512 + b * 256))[lane];
    f4 wv = ((const f4*)(W1 + (size_t)o * 256))[lane];
    float acc = wv[0]*iv[0] + wv[1]*iv[1] + wv[2]*iv[2] + wv[3]*iv[3];
    #pragma unroll
    for (int off = 32; off > 0; off >>= 1) acc += __shfl_down(acc, off, 64);
    if (lane == 0) {
        acc += b1[o];
        f1v[wave] = acc > 0.f ? acc : 0.01f * acc;
    }
}

// K5: fc2 — one wave per output, K=1024 (4 f4/lane), butterfly reduce.
__global__ __launch_bounds__(256) void k_fc2(const float* __restrict__ f1v, const float* __restrict__ W2,
                                             const float* __restrict__ b2, float* __restrict__ f2v) {
    int wave = blockIdx.x * 4 + (threadIdx.x >> 6);   // 0..1023
    int lane = threadIdx.x & 63;
    int b = wave >> 9, o = wave & 511;
    const f4* w2r = (const f4*)(W2 + (size_t)o * 1024);
    const f4* i2r = (const f4*)(f1v + b * 1024);
    float acc = 0.f;
    #pragma unroll
    for (int c2 = 0; c2 < 4; ++c2) {
        f4 wv = w2r[c2 * 64 + lane];
        f4 iv = i2r[c2 * 64 + lane];
        acc += wv[0]*iv[0] + wv[1]*iv[1] + wv[2]*iv[2] + wv[3]*iv[3];
    }
    #pragma unroll
    for (int off = 32; off > 0; off >>= 1) acc += __shfl_down(acc, off, 64);
    if (lane == 0) {
        acc += b2[o];
        f2v[wave] = acc > 0.f ? acc : 0.01f * acc;
    }
}

// K6: fc3 + predict; grid(2) — block b handles its batch only (pred[b] needs f3[b] only).
__global__ __launch_bounds__(256) void k_f3p(const float* __restrict__ f2v, const float* __restrict__ W3,
                                             const float* __restrict__ b3, const float* __restrict__ Wo,
                                             const float* __restrict__ bo, float* __restrict__ out) {
    __shared__ float f3s[256];
    int b = blockIdx.x, tid = threadIdx.x;
    const f4* w3r = (const f4*)(W3 + (size_t)tid * 512);
    const f4* f2b = (const f4*)(f2v + b * 512);
    float a0 = b3[tid];
    #pragma unroll 4
    for (int c2 = 0; c2 < 128; ++c2) {
        f4 wv4 = w3r[c2];
        f4 i0 = f2b[c2];
        a0 += wv4[0]*i0[0] + wv4[1]*i0[1] + wv4[2]*i0[2] + wv4[3]*i0[3];
    }
    f3s[tid] = a0 > 0.f ? a0 : 0.01f * a0;
    __syncthreads();
    int wvid = tid >> 6, lane = tid & 63;
    if (wvid < 2) {
        int o = wvid;
        f4 wo4 = ((const f4*)(Wo + o * 256))[lane];
        float acc = wo4[0]*f3s[lane*4] + wo4[1]*f3s[lane*4+1]
                  + wo4[2]*f3s[lane*4+2] + wo4[3]*f3s[lane*4+3];
        #pragma unroll
        for (int off = 32; off > 0; off >>= 1) acc += __shfl_down(acc, off, 64);
        if (lane == 0) out[b * 2 + o] = acc + bo[o];
    }
}

extern "C" void kernel_launch(void* const* d_in, const int* in_sizes, int n_in,
                              void* d_out, int out_size, void* d_ws, size_t ws_size,
                              hipStream_t stream) {
    (void)in_sizes; (void)n_in; (void)out_size; (void)ws_size;
    const float* v0 = (const float*)d_in[0];
    const float* v1 = (const float*)d_in[1];
    const float* v2 = (const float*)d_in[2];
    const float* vt = (const float*)d_in[3];
    const float* vl = (const float*)d_in[4];
    const float* Wt = (const float*)d_in[5];
    const float* bt = (const float*)d_in[6];
    const float* Wl = (const float*)d_in[7];
    const float* bl = (const float*)d_in[8];
    const float* Wa = (const float*)d_in[9];
    const float* ba = (const float*)d_in[10];
    const float* W1 = (const float*)d_in[11];
    const float* b1 = (const float*)d_in[12];
    const float* W2 = (const float*)d_in[13];
    const float* b2 = (const float*)d_in[14];
    const float* W3 = (const float*)d_in[15];
    const float* b3 = (const float*)d_in[16];
    const float* Wo = (const float*)d_in[17];
    const float* bo = (const float*)d_in[18];

    float* ws   = (float*)d_ws;
    float* attT = ws;                 // [2][2][128][544] = 278528
    float* S    = ws + 278528;        // [2][2][544][128] = 278528
    float* x4   = ws + 557056;        // [4][2][256]      = 2048
    float* f1v  = ws + 559104;        // [2][1024]
    float* f2v  = ws + 561152;        // [2][512]
    float* WT   = ws + 562176;        // [3][128][128]    = 49152
    float* out = (float*)d_out;

    k_tr<<<dim3(128, 3), 128, 0, stream>>>(Wt, Wl, Wa, WT);
    k_att<<<dim3(136, 2, 2), 128, 0, stream>>>(v0, v1, v2, vt, vl, WT, bt, bl, attT, x4);
    k_pair<<<dim3(128, 2, 2), 256, 0, stream>>>(attT, S);
    k_atte<<<dim3(136, 2, 2), 128, 0, stream>>>(S, WT, ba, v0, v1, v2, vt, vl, out, x4);
    k_fc1<<<512, 256, 0, stream>>>(x4, W1, b1, f1v);
    k_fc2<<<256, 256, 0, stream>>>(f1v, W2, b2, f2v);
    k_f3p<<<2, 256, 0, stream>>>(f2v, W3, b3, Wo, bo, out);
}